// Round 7
// baseline (236.086 us; speedup 1.0000x reference)
//
#include <hip/hip_runtime.h>
#include <hip/hip_bf16.h>
#include <math.h>

// Problem dims (fixed by reference)
#define Bq 4
#define Nq 512
#define Cq 128   // d_in
#define Oq 64    // d_mid
#define TI 16
#define TJ 8
#define NBLK (Bq*(Nq/TI)*(Nq/TJ))   // 8192 pair-blocks
#define PTOT ((double)Bq*Nq*Nq)     // 1048576 pairs (BN2d population)
#define NROW (Bq*Nq)                // 2048 rows
#define EPSq 1e-5f
#define NEGq -9e15f

typedef _Float16 half8 __attribute__((ext_vector_type(8)));
typedef float f32x4 __attribute__((ext_vector_type(4)));

// ---- workspace layout (bytes) — UNCHANGED from round 6 ----
#define OFF_S       0u          // s / A in-place: 4 MiB
#define OFF_YAGG    4194304u    // [2048][128] f32
#define OFF_YFC     5242880u    // [2048][128] f32
#define OFF_WGT     6291456u    // WgT [128][128] f32 (c-major)
#define OFF_WTT     6356992u    // WtT [256][128] f32 (k-major)
#define OFF_WF      6488064u    // W1 fp16 in MFMA frag order [4ks][4nt][64lane][8e]
#define OFF_PART1   6504448u    // partial1 [8192][128] f32
#define OFF_RED1    10698752u   // double[128] (unused now, kept for layout stability)
#define OFF_SC1     10699776u   // float scale1[64], shift1[64]
#define OFF_PARTG   10700288u   // partialg [256][256] f32
#define OFF_SCG     10962432u   // float scaleg[128], shiftg[128]
#define WS_NEED     10963456u

__device__ __forceinline__ float lrelu(float v) { return v >= 0.0f ? v : 0.01f * v; }

// ============================================================================
// Pair core: h[p,o] = sum_c |x_i - x_j|_c * W1[o,c]  via fp16 MFMA 16x16x32.
// Block: 128 pairs (16 i x 8 j) x 64 outputs x K=128. 4 waves; wave wv owns
// Mtiles {2wv, 2wv+1} (32 pairs) and all 4 Ntiles.
// B-frags preloaded from Wf (frag-order) and PINNED in VGPRs via empty asm —
// round-6 run showed VGPR_Count=56: compiler rematerialized the 16 invariant
// global loads inside the MFMA loop (MfmaUtil 15%, stall-bound). The pin
// makes the loaded values opaque so regalloc must keep them resident.
// C/D: col = l&15 (output), row = 4*(l>>4)+reg (pair) [m89-verified].
// MODE 0: BN stats (sum/sumsq of raw h). MODE 1: normalized->lrelu->W2->mask.
// ============================================================================
template <int MODE>
__global__ __launch_bounds__(256, 3) void k_pair_mfma(
    const float* __restrict__ x, const _Float16* __restrict__ Wf,
    const int* __restrict__ A_init, const float* __restrict__ W2,
    const float* __restrict__ b2, const float* __restrict__ scsh,
    float* __restrict__ partial1, float* __restrict__ s_buf) {
  __shared__ float XI[TI][136];
  __shared__ float XJ[TJ][136];
  __shared__ float ep[4][2][64];   // MODE0 cross-wave stats
  __shared__ float ssc[128];       // MODE1 score bounce

  const int t = threadIdx.x;
  const int l = t & 63;
  const int wv = __builtin_amdgcn_readfirstlane(t >> 6);
  const int jt = blockIdx.x, it = blockIdx.y, b = blockIdx.z;
  const int i0 = it * TI, j0 = jt * TJ;
  const float* xb = x + (size_t)b * Nq * Cq;

  // ---- B-frags: 16 x 16B = 64 VGPR, coalesced dwordx4 loads (issued first,
  //      latency overlaps the XI/XJ staging below) ----
  float4 bfr[16];
#pragma unroll
  for (int i = 0; i < 16; ++i)
    bfr[i] = *(const float4*)&Wf[(size_t)(i * 64 + l) * 8];

  // ---- stage XI, XJ (pad 136 floats) ----
  {
    const int row = t >> 4, col = (t & 15) * 8;
    const float* src = xb + (size_t)(i0 + row) * Cq + col;
    *(float4*)&XI[row][col] = *(const float4*)src;
    *(float4*)&XI[row][col + 4] = *(const float4*)(src + 4);
    if (t < 128) {
      const int rj = t >> 4;
      const float* sj = xb + (size_t)(j0 + rj) * Cq + col;
      *(float4*)&XJ[rj][col] = *(const float4*)sj;
      *(float4*)&XJ[rj][col + 4] = *(const float4*)(sj + 4);
    }
  }
  __syncthreads();

  // pin bf values in VGPRs (after the barrier so staging overlapped the loads)
#pragma unroll
  for (int i = 0; i < 16; ++i)
    asm volatile("" : "+v"(bfr[i].x), "+v"(bfr[i].y), "+v"(bfr[i].z), "+v"(bfr[i].w));

  const int g = l >> 4;        // k-group 0..3
  const int cL = l & 15;
  const int jlan = l & 7;
  const int ilh = (l >> 3) & 1;

  f32x4 zero;
  zero[0] = 0.0f; zero[1] = 0.0f; zero[2] = 0.0f; zero[3] = 0.0f;
  f32x4 acc[2][4];
#pragma unroll
  for (int m = 0; m < 2; ++m)
#pragma unroll
    for (int n = 0; n < 4; ++n) acc[m][n] = zero;

#pragma unroll
  for (int ks = 0; ks < 4; ++ks) {
#pragma unroll
    for (int m = 0; m < 2; ++m) {
      const int mt = wv * 2 + m;
      const int il = mt * 2 + ilh;          // (mt*16 + cL) >> 3
      const int c0 = ks * 32 + 4 * g;
      const float4 a0 = *(const float4*)&XI[il][c0];
      const float4 a1 = *(const float4*)&XI[il][c0 + 16];
      const float4 v0 = *(const float4*)&XJ[jlan][c0];
      const float4 v1 = *(const float4*)&XJ[jlan][c0 + 16];
      half8 af;
      af[0] = (_Float16)fabsf(a0.x - v0.x);
      af[1] = (_Float16)fabsf(a0.y - v0.y);
      af[2] = (_Float16)fabsf(a0.z - v0.z);
      af[3] = (_Float16)fabsf(a0.w - v0.w);
      af[4] = (_Float16)fabsf(a1.x - v1.x);
      af[5] = (_Float16)fabsf(a1.y - v1.y);
      af[6] = (_Float16)fabsf(a1.z - v1.z);
      af[7] = (_Float16)fabsf(a1.w - v1.w);
#pragma unroll
      for (int n = 0; n < 4; ++n)
        acc[m][n] = __builtin_amdgcn_mfma_f32_16x16x32_f16(
            af, __builtin_bit_cast(half8, bfr[ks * 4 + n]), acc[m][n], 0, 0, 0);
    }
  }

  const int blk = ((b * (Nq / TI) + it) * (Nq / TJ) + jt);

  if (MODE == 0) {
    // per-channel sum/sumsq over the wave's 32 pairs, then cross-wave via LDS
#pragma unroll
    for (int n = 0; n < 4; ++n) {
      float a = 0.0f, q = 0.0f;
#pragma unroll
      for (int m = 0; m < 2; ++m)
#pragma unroll
        for (int r = 0; r < 4; ++r) {
          const float v = acc[m][n][r];
          a += v;
          q += v * v;
        }
      a += __shfl_xor(a, 16); a += __shfl_xor(a, 32);
      q += __shfl_xor(q, 16); q += __shfl_xor(q, 32);
      if (l < 16) {
        ep[wv][0][n * 16 + l] = a;
        ep[wv][1][n * 16 + l] = q;
      }
    }
    __syncthreads();
    if (t < 128) {
      const int o = t & 63, typ = t >> 6;
      const float v = ep[0][typ][o] + ep[1][typ][o] + ep[2][typ][o] + ep[3][typ][o];
      partial1[(size_t)blk * 128 + typ * 64 + o] = v;
    }
    return;
  }

  // ---- MODE 1: BN-normalize -> lrelu -> dot W2 -> mask -> scores ----
  float sc[4], sh[4], w2[4];
#pragma unroll
  for (int n = 0; n < 4; ++n) {
    const int o = n * 16 + cL;
    sc[n] = scsh[o];
    sh[n] = scsh[64 + o];
    w2[n] = W2[o];
  }
  float sp[2][4];
#pragma unroll
  for (int m = 0; m < 2; ++m)
#pragma unroll
    for (int r = 0; r < 4; ++r) {
      float v = 0.0f;
#pragma unroll
      for (int n = 0; n < 4; ++n) {
        float h = fmaf(acc[m][n][r], sc[n], sh[n]);
        h = lrelu(h);
        v = fmaf(w2[n], h, v);
      }
      v += __shfl_xor(v, 1);
      v += __shfl_xor(v, 2);
      v += __shfl_xor(v, 4);
      v += __shfl_xor(v, 8);
      sp[m][r] = v;
    }
  if (cL == 0) {
#pragma unroll
    for (int m = 0; m < 2; ++m)
#pragma unroll
      for (int r = 0; r < 4; ++r) ssc[wv * 32 + m * 16 + 4 * g + r] = sp[m][r];
  }
  __syncthreads();
  if (t < 128) {
    const int il2 = t >> 3, jl2 = t & 7;
    const size_t arow = ((size_t)b * Nq + (i0 + il2)) * Nq + (j0 + jl2);
    s_buf[arow] = (A_init[arow] > 0) ? ssc[t] + b2[0] : NEGq;
  }
}

// ============================================================================
// Fused BN1 stats reduction + finalize: 64 blocks, block o handles channel o
// (sum at col o, sumsq at col 64+o of partial1), writes scale/shift directly.
__global__ __launch_bounds__(256) void k_stats1(const float* __restrict__ partial1,
                                                const float* __restrict__ g1,
                                                const float* __restrict__ be1,
                                                float* __restrict__ scsh) {
  __shared__ float sh[2][256];
  const int o = blockIdx.x;   // 0..63
  const int t = threadIdx.x;
  float s = 0.0f, q = 0.0f;
  for (int blk = t; blk < NBLK; blk += 256) {
    s += partial1[(size_t)blk * 128 + o];
    q += partial1[(size_t)blk * 128 + 64 + o];
  }
  sh[0][t] = s;
  sh[1][t] = q;
  __syncthreads();
  for (int off = 128; off > 0; off >>= 1) {
    if (t < off) {
      sh[0][t] += sh[0][t + off];
      sh[1][t] += sh[1][t + off];
    }
    __syncthreads();
  }
  if (t == 0) {
    const double m_raw = (double)sh[0][0] / PTOT;
    double var = (double)sh[1][0] / PTOT - m_raw * m_raw;
    if (var < 0.0) var = 0.0;
    const float scale = g1[o] / sqrtf((float)var + EPSq);
    scsh[o] = scale;
    scsh[64 + o] = be1[o] - (float)m_raw * scale;  // b1 cancels exactly
  }
}

__global__ __launch_bounds__(256) void k_softmax(float* __restrict__ s) {
  __shared__ float r1[4];
  const size_t row = blockIdx.x;
  float* p = s + row * Nq;
  const int t = threadIdx.x;
  float2 v = *(float2*)&p[t * 2];
  float mx = fmaxf(v.x, v.y);
#pragma unroll
  for (int off = 32; off > 0; off >>= 1) mx = fmaxf(mx, __shfl_xor(mx, off));
  if ((t & 63) == 0) r1[t >> 6] = mx;
  __syncthreads();
  mx = fmaxf(fmaxf(r1[0], r1[1]), fmaxf(r1[2], r1[3]));
  const float e0 = expf(v.x - mx), e1 = expf(v.y - mx);
  float ss = e0 + e1;
#pragma unroll
  for (int off = 32; off > 0; off >>= 1) ss += __shfl_xor(ss, off);
  __syncthreads();
  if ((t & 63) == 0) r1[t >> 6] = ss;
  __syncthreads();
  const float tot = r1[0] + r1[1] + r1[2] + r1[3];
  float2 o2;
  o2.x = e0 / tot;
  o2.y = e1 / tot;
  *(float2*)&p[t * 2] = o2;
}

// y = A@x: 512 blocks x 256 thr; 4 rows/block, j-range split across the two
// thread-halves (halves the serial FMA chain, doubles waves/CU), LDS combine.
__global__ __launch_bounds__(256) void k_yagg(const float* __restrict__ A,
                                              const float* __restrict__ x,
                                              float* __restrict__ y) {
  __shared__ float red[4][128];
  const int r0 = blockIdx.x * 4;          // 4 rows, never straddles a batch
  const int b = r0 >> 9;
  const int t = threadIdx.x;
  const int hf = t >> 7, c = t & 127;     // hf: j-half, c: channel
  const float* xb = x + (size_t)b * Nq * Cq + (size_t)hf * 256 * Cq + c;
  const float* Ar = A + (size_t)r0 * Nq + hf * 256;
  float a0 = 0.0f, a1 = 0.0f, a2 = 0.0f, a3 = 0.0f;
#pragma unroll 2
  for (int j = 0; j < 256; j += 4) {
    const float4 c0 = *(const float4*)&Ar[j];
    const float4 c1 = *(const float4*)&Ar[Nq + j];
    const float4 c2 = *(const float4*)&Ar[2 * Nq + j];
    const float4 c3 = *(const float4*)&Ar[3 * Nq + j];
    const float x0 = xb[(size_t)j * Cq];
    const float x1 = xb[(size_t)(j + 1) * Cq];
    const float x2 = xb[(size_t)(j + 2) * Cq];
    const float x3 = xb[(size_t)(j + 3) * Cq];
    a0 = fmaf(c0.x, x0, a0); a0 = fmaf(c0.y, x1, a0);
    a0 = fmaf(c0.z, x2, a0); a0 = fmaf(c0.w, x3, a0);
    a1 = fmaf(c1.x, x0, a1); a1 = fmaf(c1.y, x1, a1);
    a1 = fmaf(c1.z, x2, a1); a1 = fmaf(c1.w, x3, a1);
    a2 = fmaf(c2.x, x0, a2); a2 = fmaf(c2.y, x1, a2);
    a2 = fmaf(c2.z, x2, a2); a2 = fmaf(c2.w, x3, a2);
    a3 = fmaf(c3.x, x0, a3); a3 = fmaf(c3.y, x1, a3);
    a3 = fmaf(c3.z, x2, a3); a3 = fmaf(c3.w, x3, a3);
  }
  if (hf) {
    red[0][c] = a0; red[1][c] = a1; red[2][c] = a2; red[3][c] = a3;
  }
  __syncthreads();
  if (!hf) {
    y[(size_t)(r0 + 0) * Cq + c] = a0 + red[0][c];
    y[(size_t)(r0 + 1) * Cq + c] = a1 + red[1][c];
    y[(size_t)(r0 + 2) * Cq + c] = a2 + red[2][c];
    y[(size_t)(r0 + 3) * Cq + c] = a3 + red[3][c];
  }
}

// yfc: 256 blocks x 512 thr, 8 rows/block, 2 cols/thread (512-FMA -> 256-FMA
// chains, 8 waves/CU). Stats partials unchanged layout [256][256].
__global__ __launch_bounds__(512) void k_yfc(const float* __restrict__ y,
                                             const float* __restrict__ WgT,
                                             const float* __restrict__ bg,
                                             float* __restrict__ yfc,
                                             float* __restrict__ partialg) {
  __shared__ float Y[8][128];
  __shared__ float red[8][128];
  const int n0 = blockIdx.x * 8;
  const int t = threadIdx.x;
  const int r = t >> 6, c2 = (t & 63) * 2;
  *(float2*)&Y[r][c2] = *(const float2*)&y[(size_t)(n0 + r) * 128 + c2];
  __syncthreads();
  const float2 bv = *(const float2*)&bg[c2];
  float a0 = bv.x, a1 = bv.y;
#pragma unroll 4
  for (int c = 0; c < 128; ++c) {
    const float yv = Y[r][c];
    const float2 w = *(const float2*)&WgT[(size_t)c * 128 + c2];
    a0 = fmaf(yv, w.x, a0);
    a1 = fmaf(yv, w.y, a1);
  }
  *(float2*)&yfc[(size_t)(n0 + r) * 128 + c2] = make_float2(a0, a1);
  red[r][c2] = a0;
  red[r][c2 + 1] = a1;
  __syncthreads();
  if (t < 256) {
    const int ch = t & 127, typ = t >> 7;
    float v = 0.0f;
    if (typ == 0) {
#pragma unroll
      for (int rr = 0; rr < 8; ++rr) v += red[rr][ch];
    } else {
#pragma unroll
      for (int rr = 0; rr < 8; ++rr) v += red[rr][ch] * red[rr][ch];
    }
    partialg[(size_t)blockIdx.x * 256 + typ * 128 + ch] = v;
  }
}

__global__ void k_finalizeg(const float* __restrict__ partialg, const float* __restrict__ gg,
                            const float* __restrict__ beg, float* __restrict__ scg) {
  const int h = threadIdx.x;  // 128
  double s = 0.0, q = 0.0;
  for (int blk = 0; blk < 256; ++blk) {
    s += (double)partialg[(size_t)blk * 256 + h];
    q += (double)partialg[(size_t)blk * 256 + 128 + h];
  }
  const double m = s / (double)NROW;
  double var = q / (double)NROW - m * m;
  if (var < 0.0) var = 0.0;
  const float scale = gg[h] / sqrtf((float)var + EPSq);
  scg[h] = scale;
  scg[128 + h] = beg[h] - (float)m * scale;
}

// out: 256 blocks x 512 thr, 8 rows/block, 2 cols/thread.
__global__ __launch_bounds__(512) void k_out(const float* __restrict__ x,
                                             const float* __restrict__ yfc,
                                             const float* __restrict__ WtT,
                                             const float* __restrict__ bt,
                                             const float* __restrict__ scg,
                                             float* __restrict__ out) {
  __shared__ float XZ[8][256];
  const int n0 = blockIdx.x * 8;
  const int t = threadIdx.x;
  const int r = t >> 6, c2 = (t & 63) * 2;
  *(float2*)&XZ[r][c2] = *(const float2*)&x[(size_t)(n0 + r) * 128 + c2];
  {
    const float2 yv = *(const float2*)&yfc[(size_t)(n0 + r) * 128 + c2];
    const float2 s0 = *(const float2*)&scg[c2];
    const float2 s1 = *(const float2*)&scg[128 + c2];
    XZ[r][128 + c2 + 0] = lrelu(fmaf(yv.x, s0.x, s1.x));
    XZ[r][128 + c2 + 1] = lrelu(fmaf(yv.y, s0.y, s1.y));
  }
  __syncthreads();
  const float2 bv = *(const float2*)&bt[c2];
  float a0 = bv.x, a1 = bv.y;
#pragma unroll 4
  for (int c = 0; c < 256; ++c) {
    const float xv = XZ[r][c];
    const float2 w = *(const float2*)&WtT[(size_t)c * 128 + c2];
    a0 = fmaf(xv, w.x, a0);
    a1 = fmaf(xv, w.y, a1);
  }
  *(float2*)&out[(size_t)(n0 + r) * 128 + c2] = make_float2(a0, a1);
}

// WgT (c-major), WtT (k-major), Wf = W1 as fp16 in exact MFMA B-frag order.
__global__ void k_prep(const float* __restrict__ Wg, const float* __restrict__ Wt,
                       const float* __restrict__ W1, float* __restrict__ WgT,
                       float* __restrict__ WtT, _Float16* __restrict__ Wf) {
  const int idx = blockIdx.x * 256 + threadIdx.x;
  if (idx < 16384) {
    const int h = idx >> 7, c = idx & 127;
    WgT[(size_t)c * 128 + h] = Wg[idx];
  } else if (idx < 49152) {
    const int k2 = idx - 16384;
    const int o = k2 >> 8, k = k2 & 255;
    WtT[(size_t)k * 128 + o] = Wt[k2];
  } else if (idx < 57344) {
    const int f = idx - 49152;
    const int e = f & 7, lane = (f >> 3) & 63, nt = (f >> 9) & 3, ks = f >> 11;
    const int k = ks * 32 + 4 * (lane >> 4) + ((e < 4) ? e : (12 + e));  // +16 for hi half
    const int o = nt * 16 + (lane & 15);
    Wf[f] = (_Float16)W1[o * 128 + k];
  }
}

extern "C" void kernel_launch(void* const* d_in, const int* in_sizes, int n_in,
                              void* d_out, int out_size, void* d_ws, size_t ws_size,
                              hipStream_t stream) {
  const float* x = (const float*)d_in[0];
  const int* A_init = (const int*)d_in[1];
  const float* W1 = (const float*)d_in[2];
  // d_in[3] = b1 (cancels in BN affine fold)
  const float* g1 = (const float*)d_in[4];
  const float* be1 = (const float*)d_in[5];
  const float* W2 = (const float*)d_in[6];
  const float* b2 = (const float*)d_in[7];
  const float* Wg = (const float*)d_in[8];
  const float* bg = (const float*)d_in[9];
  const float* gg = (const float*)d_in[10];
  const float* beg = (const float*)d_in[11];
  const float* Wt = (const float*)d_in[12];
  const float* bt = (const float*)d_in[13];
  float* out = (float*)d_out;

  char* ws = (char*)d_ws;
  if (ws_size < WS_NEED) return;
  float* sA = (float*)(ws + OFF_S);
  float* yagg = (float*)(ws + OFF_YAGG);
  float* yfc = (float*)(ws + OFF_YFC);
  float* WgT = (float*)(ws + OFF_WGT);
  float* WtT = (float*)(ws + OFF_WTT);
  _Float16* Wf = (_Float16*)(ws + OFF_WF);
  float* partial1 = (float*)(ws + OFF_PART1);
  float* scsh1 = (float*)(ws + OFF_SC1);
  float* partialg = (float*)(ws + OFF_PARTG);
  float* scg = (float*)(ws + OFF_SCG);

  k_prep<<<224, 256, 0, stream>>>(Wg, Wt, W1, WgT, WtT, Wf);

  dim3 gpass(Nq / TJ, Nq / TI, Bq);  // 64 x 32 x 4
  k_pair_mfma<0><<<gpass, 256, 0, stream>>>(x, Wf, A_init, W2, b2, scsh1, partial1, sA);
  k_stats1<<<64, 256, 0, stream>>>(partial1, g1, be1, scsh1);
  k_pair_mfma<1><<<gpass, 256, 0, stream>>>(x, Wf, A_init, W2, b2, scsh1, partial1, sA);
  k_softmax<<<NROW, 256, 0, stream>>>(sA);
  k_yagg<<<NROW / 4, 256, 0, stream>>>(sA, x, yagg);
  k_yfc<<<NROW / 8, 512, 0, stream>>>(yagg, WgT, bg, yfc, partialg);
  k_finalizeg<<<1, 128, 0, stream>>>(partialg, gg, beg, scg);
  k_out<<<NROW / 8, 512, 0, stream>>>(x, yfc, WtT, bt, scg, out);
}